// Round 1
// baseline (43.084 us; speedup 1.0000x reference)
//
#include <hip/hip_runtime.h>

// Sparsemax over last axis. B=8, N=4096, D=512, fp32 in/out.
// One 64-lane wave per row; 8 values/lane in registers.
// Tau found via Michelot's fixed-point iteration (exact, sort-free):
//   tau_{k+1} = (sum_{z > tau_k} z - 1) / |{z > tau_k}|
// Support shrinks monotonically -> converges in a handful of iterations.

constexpr int D   = 512;
constexpr int NW  = 64;        // wave width
constexpr int VPT = D / NW;    // 8 values per lane

__global__ __launch_bounds__(256)
void sparsemax_kernel(const float* __restrict__ in, float* __restrict__ out,
                      int nrows) {
    const int lane = threadIdx.x & (NW - 1);
    const int wave = threadIdx.x >> 6;
    const int row  = blockIdx.x * (blockDim.x >> 6) + wave;
    if (row >= nrows) return;

    const float* rp = in  + (size_t)row * D;
    float*       op = out + (size_t)row * D;

    // Coalesced: chunk 0 = floats [0,256), chunk 1 = [256,512); lane reads float4.
    const float4 a = reinterpret_cast<const float4*>(rp)[lane];
    const float4 b = reinterpret_cast<const float4*>(rp)[NW + lane];

    float v[VPT] = {a.x, a.y, a.z, a.w, b.x, b.y, b.z, b.w};

    // ---- initial tau over full support ----
    float s = 0.f;
#pragma unroll
    for (int i = 0; i < VPT; ++i) s += v[i];
#pragma unroll
    for (int off = 32; off; off >>= 1) s += __shfl_xor(s, off, NW);
    float tau = (s - 1.0f) * (1.0f / (float)D);

    // ---- Michelot fixed-point: support strictly shrinks until stable ----
    int prev_cnt = D;
    for (int it = 0; it < 512; ++it) {
        float ps = 0.f;
        int   pc = 0;
#pragma unroll
        for (int i = 0; i < VPT; ++i) {
            const bool g = v[i] > tau;
            ps += g ? v[i] : 0.0f;
            pc += g ? 1 : 0;
        }
#pragma unroll
        for (int off = 32; off; off >>= 1) {
            ps += __shfl_xor(ps, off, NW);
            pc += __shfl_xor(pc, off, NW);
        }
        tau = (ps - 1.0f) / (float)pc;   // pc >= 1 always (max elem > tau)
        if (pc == prev_cnt) break;       // support unchanged -> converged
        prev_cnt = pc;
    }

    // ---- output: relu(z - tau), coalesced float4 stores ----
    float4 oa, ob;
    oa.x = fmaxf(v[0] - tau, 0.0f);
    oa.y = fmaxf(v[1] - tau, 0.0f);
    oa.z = fmaxf(v[2] - tau, 0.0f);
    oa.w = fmaxf(v[3] - tau, 0.0f);
    ob.x = fmaxf(v[4] - tau, 0.0f);
    ob.y = fmaxf(v[5] - tau, 0.0f);
    ob.z = fmaxf(v[6] - tau, 0.0f);
    ob.w = fmaxf(v[7] - tau, 0.0f);
    reinterpret_cast<float4*>(op)[lane]      = oa;
    reinterpret_cast<float4*>(op)[NW + lane] = ob;
}

extern "C" void kernel_launch(void* const* d_in, const int* in_sizes, int n_in,
                              void* d_out, int out_size, void* d_ws, size_t ws_size,
                              hipStream_t stream) {
    const float* in  = (const float*)d_in[0];   // inputs [B,N,D]; mask (d_in[1]) unused
    float*       out = (float*)d_out;
    const int nrows = out_size / D;             // 8*4096 = 32768

    const int waves_per_block = 4;              // 256 threads
    const int rows_per_block  = waves_per_block;
    const int grid = (nrows + rows_per_block - 1) / rows_per_block;
    sparsemax_kernel<<<grid, 256, 0, stream>>>(in, out, nrows);
}

// Round 2
// 24.186 us; speedup vs baseline: 1.7814x; 1.7814x over previous
//
#include <hip/hip_runtime.h>

// Sparsemax over last axis. B=8, N=4096, D=512, fp32 in/out.
// One 64-lane wave per row; 8 values/lane in registers.
// Tau via Michelot fixed-point, but started at tau0 = max-1 (valid lower
// bound on tau*: max weight <= 1), which shrinks the initial support from
// 512 to ~a dozen for Gaussian data. Counts come from ballot+popcount
// (scalar pipe) instead of a second shuffle reduction.

constexpr int D   = 512;
constexpr int NW  = 64;        // wave width
constexpr int VPT = D / NW;    // 8 values per lane

__global__ __launch_bounds__(256)
void sparsemax_kernel(const float* __restrict__ in, float* __restrict__ out,
                      int nrows) {
    const int lane = threadIdx.x & (NW - 1);
    const int wave = threadIdx.x >> 6;
    const int row  = blockIdx.x * 4 + wave;
    if (row >= nrows) return;

    const float* rp = in  + (size_t)row * D;
    float*       op = out + (size_t)row * D;

    const float4 a = reinterpret_cast<const float4*>(rp)[lane];
    const float4 b = reinterpret_cast<const float4*>(rp)[NW + lane];
    float v[VPT] = {a.x, a.y, a.z, a.w, b.x, b.y, b.z, b.w};

    // ---- wave max ----
    float m = v[0];
#pragma unroll
    for (int i = 1; i < VPT; ++i) m = fmaxf(m, v[i]);
#pragma unroll
    for (int off = 32; off; off >>= 1) m = fmaxf(m, __shfl_xor(m, off, NW));

    // ---- Michelot fixed-point from tau0 = max - 1 ----
    float tau  = m - 1.0f;
    int   prev = 1 << 30;
    for (int it = 0; it < D; ++it) {
        float ps = 0.f;
        int   pc = 0;
#pragma unroll
        for (int i = 0; i < VPT; ++i) {
            const bool g = v[i] > tau;
            ps += g ? v[i] : 0.0f;
            pc += (int)__popcll(__ballot(g));   // uniform mask -> s_bcnt1_b64
        }
#pragma unroll
        for (int off = 32; off; off >>= 1) ps += __shfl_xor(ps, off, NW);
        tau = (ps - 1.0f) / (float)pc;          // pc >= 1 (max > max-1)
        if (pc >= prev) break;                  // support stopped shrinking
        prev = pc;
    }

    // ---- output: relu(z - tau), coalesced float4 stores ----
    float4 oa, ob;
    oa.x = fmaxf(v[0] - tau, 0.0f);
    oa.y = fmaxf(v[1] - tau, 0.0f);
    oa.z = fmaxf(v[2] - tau, 0.0f);
    oa.w = fmaxf(v[3] - tau, 0.0f);
    ob.x = fmaxf(v[4] - tau, 0.0f);
    ob.y = fmaxf(v[5] - tau, 0.0f);
    ob.z = fmaxf(v[6] - tau, 0.0f);
    ob.w = fmaxf(v[7] - tau, 0.0f);
    reinterpret_cast<float4*>(op)[lane]      = oa;
    reinterpret_cast<float4*>(op)[NW + lane] = ob;
}

extern "C" void kernel_launch(void* const* d_in, const int* in_sizes, int n_in,
                              void* d_out, int out_size, void* d_ws, size_t ws_size,
                              hipStream_t stream) {
    const float* in  = (const float*)d_in[0];   // inputs [B,N,D]; mask unused
    float*       out = (float*)d_out;
    const int nrows = out_size / D;             // 32768

    const int grid = (nrows + 3) / 4;           // 4 waves/block, 1 row/wave
    sparsemax_kernel<<<grid, 256, 0, stream>>>(in, out, nrows);
}